// Round 1
// baseline (4059.029 us; speedup 1.0000x reference)
//
#include <hip/hip_runtime.h>
#include <hip/hip_bf16.h>

#define DEVFN __device__ __forceinline__

constexpr int NN = 50000;   // nodes
constexpr int NE = 600000;  // edges
constexpr int NG = 256;     // graphs
constexpr int FN = 92;      // node feat
constexpr int FE = 50;      // edge feat
constexpr int H  = 128;     // hidden
constexpr int NL = 3;       // layers

static_assert(NE % 32 == 0, "edge tile");
static_assert(NN % 8 == 0, "node tile");

// ---------- dtype helpers (float or bf16 storage of e) ----------
DEVFN float4 load4e(const float* p) { return *reinterpret_cast<const float4*>(p); }
DEVFN float4 load4e(const __hip_bfloat16* p) {
    const ushort4 u = *reinterpret_cast<const ushort4*>(p);
    float4 r;
    r.x = __uint_as_float(((unsigned)u.x) << 16);
    r.y = __uint_as_float(((unsigned)u.y) << 16);
    r.z = __uint_as_float(((unsigned)u.z) << 16);
    r.w = __uint_as_float(((unsigned)u.w) << 16);
    return r;
}
DEVFN void store4e(float* p, float4 v) { *reinterpret_cast<float4*>(p) = v; }
DEVFN void store4e(__hip_bfloat16* p, float4 v) {
    p[0] = __float2bfloat16(v.x);
    p[1] = __float2bfloat16(v.y);
    p[2] = __float2bfloat16(v.z);
    p[3] = __float2bfloat16(v.w);
}

// ---------- out[r][f] = X[r,:K] @ W[:K,f] (+ bias) ----------
// 8 rows per block, 128 threads (one per output feature).
template<int K>
__global__ void k_rowmm(const float* __restrict__ X, const float* __restrict__ W,
                        const float* __restrict__ bias, float* __restrict__ out,
                        int nrows)
{
    __shared__ float xs[8][K];
    const int row0 = blockIdx.x * 8;
    const int f = threadIdx.x;
    for (int idx = threadIdx.x; idx < 8 * K; idx += 128) {
        const int r = idx / K, k = idx - r * K;
        const int gr = row0 + r;
        xs[r][k] = (gr < nrows) ? X[(size_t)gr * K + k] : 0.f;
    }
    __syncthreads();
    float acc[8];
#pragma unroll
    for (int r = 0; r < 8; r++) acc[r] = 0.f;
#pragma unroll 4
    for (int k = 0; k < K; k++) {
        const float w = W[k * H + f];
#pragma unroll
        for (int r = 0; r < 8; r++) acc[r] = fmaf(xs[r][k], w, acc[r]);
    }
    const float bb = bias ? bias[f] : 0.f;
#pragma unroll
    for (int r = 0; r < 8; r++) {
        const int gr = row0 + r;
        if (gr < nrows) out[(size_t)gr * H + f] = acc[r] + bb;
    }
}

// ---------- edge MLP: e = relu(attr@W1 + b1)@W2 + b2 ----------
// 32 edges per block, 256 threads; each thread 4 edges x 4 features.
template<typename ET>
__global__ void k_edge_mlp(const float* __restrict__ attr,
                           const float* __restrict__ W1, const float* __restrict__ b1,
                           const float* __restrict__ W2, const float* __restrict__ b2,
                           ET* __restrict__ eout)
{
    __shared__ float attr_s[32][FE + 2];
    __shared__ float tmp_s[32][H + 4];
    const int e0 = blockIdx.x * 32;
    const int tg = threadIdx.x & 31;   // feature quad
    const int tr = threadIdx.x >> 5;   // edge quad group (0..7)
    const int f0 = tg * 4;

    for (int idx = threadIdx.x; idx < 32 * FE; idx += 256) {
        const int e = idx / FE, k = idx - e * FE;
        attr_s[e][k] = attr[(size_t)(e0 + e) * FE + k];
    }
    __syncthreads();

    float acc[4][4];
#pragma unroll
    for (int j = 0; j < 4; j++)
#pragma unroll
        for (int i = 0; i < 4; i++) acc[j][i] = 0.f;

#pragma unroll 2
    for (int k = 0; k < FE; k++) {
        const float4 w = *reinterpret_cast<const float4*>(&W1[k * H + f0]);
#pragma unroll
        for (int j = 0; j < 4; j++) {
            const float a = attr_s[tr * 4 + j][k];
            acc[j][0] = fmaf(a, w.x, acc[j][0]);
            acc[j][1] = fmaf(a, w.y, acc[j][1]);
            acc[j][2] = fmaf(a, w.z, acc[j][2]);
            acc[j][3] = fmaf(a, w.w, acc[j][3]);
        }
    }
    const float4 bb1 = *reinterpret_cast<const float4*>(&b1[f0]);
#pragma unroll
    for (int j = 0; j < 4; j++) {
        float4 v;
        v.x = fmaxf(acc[j][0] + bb1.x, 0.f);
        v.y = fmaxf(acc[j][1] + bb1.y, 0.f);
        v.z = fmaxf(acc[j][2] + bb1.z, 0.f);
        v.w = fmaxf(acc[j][3] + bb1.w, 0.f);
        *reinterpret_cast<float4*>(&tmp_s[tr * 4 + j][f0]) = v;
    }
    __syncthreads();

#pragma unroll
    for (int j = 0; j < 4; j++)
#pragma unroll
        for (int i = 0; i < 4; i++) acc[j][i] = 0.f;

#pragma unroll 2
    for (int k = 0; k < H; k++) {
        const float4 w = *reinterpret_cast<const float4*>(&W2[k * H + f0]);
#pragma unroll
        for (int j = 0; j < 4; j++) {
            const float a = tmp_s[tr * 4 + j][k];
            acc[j][0] = fmaf(a, w.x, acc[j][0]);
            acc[j][1] = fmaf(a, w.y, acc[j][1]);
            acc[j][2] = fmaf(a, w.z, acc[j][2]);
            acc[j][3] = fmaf(a, w.w, acc[j][3]);
        }
    }
    const float4 bb2 = *reinterpret_cast<const float4*>(&b2[f0]);
#pragma unroll
    for (int j = 0; j < 4; j++) {
        float4 v;
        v.x = acc[j][0] + bb2.x;
        v.y = acc[j][1] + bb2.y;
        v.z = acc[j][2] + bb2.z;
        v.w = acc[j][3] + bb2.w;
        store4e(&eout[(size_t)(e0 + tr * 4 + j) * H + f0], v);
    }
}

// ---------- degree / norm ----------
__global__ void k_deg(const int* __restrict__ dst, float* __restrict__ deg)
{
    const int e = blockIdx.x * 256 + threadIdx.x;
    if (e < NE) atomicAdd(&deg[dst[e]], 1.0f);
}
__global__ void k_dis(const float* __restrict__ deg, float* __restrict__ dis)
{
    const int n = blockIdx.x * 256 + threadIdx.x;
    if (n < NN) dis[n] = 1.0f / sqrtf(deg[n] + 1.0f);
}
__global__ void k_norm(const int* __restrict__ src, const int* __restrict__ dst,
                       const float* __restrict__ dis, float* __restrict__ nrm)
{
    const int e = blockIdx.x * 256 + threadIdx.x;
    if (e < NE) nrm[e] = dis[src[e]] * dis[dst[e]];
}

// ---------- scatter: agg[dst] += t[src] * e * norm ----------
template<typename ET>
__global__ void k_scatter(const float* __restrict__ t, const ET* __restrict__ ebuf,
                          const float* __restrict__ nrm,
                          const int* __restrict__ src, const int* __restrict__ dst,
                          float* __restrict__ agg)
{
    const int tid = blockIdx.x * 256 + threadIdx.x;
    const int eid = tid >> 5;
    if (eid >= NE) return;
    const int fq = (tid & 31) * 4;
    const int s = src[eid], d = dst[eid];
    const float nm = nrm[eid];
    const float4 tv = *reinterpret_cast<const float4*>(&t[(size_t)s * H + fq]);
    const float4 ev = load4e(&ebuf[(size_t)eid * H + fq]);
    float* ap = &agg[(size_t)d * H + fq];
    atomicAdd(ap + 0, tv.x * ev.x * nm);
    atomicAdd(ap + 1, tv.y * ev.y * nm);
    atomicAdd(ap + 2, tv.z * ev.z * nm);
    atomicAdd(ap + 3, tv.w * ev.w * nm);
}

// ---------- h = relu(agg + t*dis^2 + b) ----------
__global__ void k_finish(const float* __restrict__ agg, const float* __restrict__ t,
                         const float* __restrict__ dis, const float* __restrict__ bias,
                         float* __restrict__ h)
{
    const int tid = blockIdx.x * 256 + threadIdx.x;
    const int n = tid >> 5;
    if (n >= NN) return;
    const int fq = (tid & 31) * 4;
    const float ds = dis[n];
    const float d2 = ds * ds;
    const float4 a = *reinterpret_cast<const float4*>(&agg[(size_t)n * H + fq]);
    const float4 tv = *reinterpret_cast<const float4*>(&t[(size_t)n * H + fq]);
    const float4 b = *reinterpret_cast<const float4*>(&bias[fq]);
    float4 r;
    r.x = fmaxf(fmaf(tv.x, d2, a.x) + b.x, 0.f);
    r.y = fmaxf(fmaf(tv.y, d2, a.y) + b.y, 0.f);
    r.z = fmaxf(fmaf(tv.z, d2, a.z) + b.z, 0.f);
    r.w = fmaxf(fmaf(tv.w, d2, a.w) + b.w, 0.f);
    *reinterpret_cast<float4*>(&h[(size_t)n * H + fq]) = r;
}

// ---------- pooling ----------
__global__ void k_count(const int* __restrict__ batch, float* __restrict__ cnts)
{
    const int n = blockIdx.x * 256 + threadIdx.x;
    if (n < NN) atomicAdd(&cnts[batch[n]], 1.0f);
}
__global__ void k_pool(const float* __restrict__ h, const int* __restrict__ batch,
                       float* __restrict__ g)
{
    const int tid = blockIdx.x * 256 + threadIdx.x;
    const int n = tid >> 5;
    if (n >= NN) return;
    const int fq = (tid & 31) * 4;
    const int b = batch[n];
    const float4 v = *reinterpret_cast<const float4*>(&h[(size_t)n * H + fq]);
    float* gp = &g[(size_t)b * H + fq];
    atomicAdd(gp + 0, v.x);
    atomicAdd(gp + 1, v.y);
    atomicAdd(gp + 2, v.z);
    atomicAdd(gp + 3, v.w);
}

// ---------- head: out = relu(g@W1+b1)@W2 + b2 ----------
__global__ void k_head(const float* __restrict__ g, const float* __restrict__ cnts,
                       const float* __restrict__ W1, const float* __restrict__ b1,
                       const float* __restrict__ W2, const float* __restrict__ b2,
                       float* __restrict__ out)
{
    __shared__ float gs[H];
    __shared__ float red[2];
    const int gi = blockIdx.x;
    const int f = threadIdx.x;
    const float cnt = fmaxf(cnts[gi], 1.0f);
    gs[f] = g[(size_t)gi * H + f] / cnt;
    __syncthreads();
    float acc = b1[f];
#pragma unroll 4
    for (int k = 0; k < H; k++) acc = fmaf(gs[k], W1[k * H + f], acc);
    float v = fmaxf(acc, 0.f) * W2[f];
#pragma unroll
    for (int off = 32; off > 0; off >>= 1) v += __shfl_down(v, off, 64);
    if ((f & 63) == 0) red[f >> 6] = v;
    __syncthreads();
    if (f == 0) out[gi] = red[0] + red[1] + b2[0];
}

extern "C" void kernel_launch(void* const* d_in, const int* in_sizes, int n_in,
                              void* d_out, int out_size, void* d_ws, size_t ws_size,
                              hipStream_t stream)
{
    const float* x    = (const float*)d_in[0];
    const float* attr = (const float*)d_in[1];
    const int*   ei   = (const int*)d_in[2];
    const int*   bat  = (const int*)d_in[3];
    const float* Wn   = (const float*)d_in[4];
    const float* bn   = (const float*)d_in[5];
    const float* We1  = (const float*)d_in[6];
    const float* be1  = (const float*)d_in[7];
    const float* We2  = (const float*)d_in[8];
    const float* be2  = (const float*)d_in[9];
    const float* Wc   = (const float*)d_in[10];
    const float* bc   = (const float*)d_in[11];
    const float* Wl1  = (const float*)d_in[12];
    const float* bl1  = (const float*)d_in[13];
    const float* Wl2  = (const float*)d_in[14];
    const float* bl2  = (const float*)d_in[15];
    float* out = (float*)d_out;
    const int* src = ei;
    const int* dst = ei + NE;

    auto aln = [](size_t v) { return (v + 255) & ~(size_t)255; };
    char* p = (char*)d_ws;
    auto carve = [&](size_t bytes) { char* r = p; p += aln(bytes); return r; };
    float* h    = (float*)carve((size_t)NN * H * 4);
    float* t    = (float*)carve((size_t)NN * H * 4);
    float* agg  = (float*)carve((size_t)NN * H * 4);
    float* deg  = (float*)carve((size_t)NN * 4);
    float* dis  = (float*)carve((size_t)NN * 4);
    float* nrm  = (float*)carve((size_t)NE * 4);
    float* g    = (float*)carve((size_t)NG * H * 4);
    float* cnts = (float*)carve((size_t)NG * 4);
    const size_t used = (size_t)(p - (char*)d_ws);
    const bool e_f32 = (ws_size >= used + (size_t)NE * H * 4);
    void* ebuf = (void*)p;

    // 1. node embedding
    k_rowmm<FN><<<NN / 8, 128, 0, stream>>>(x, Wn, bn, h, NN);
    // 2. edge MLP
    if (e_f32)
        k_edge_mlp<float><<<NE / 32, 256, 0, stream>>>(attr, We1, be1, We2, be2, (float*)ebuf);
    else
        k_edge_mlp<__hip_bfloat16><<<NE / 32, 256, 0, stream>>>(attr, We1, be1, We2, be2, (__hip_bfloat16*)ebuf);
    // 3. degree / norm
    hipMemsetAsync(deg, 0, (size_t)NN * 4, stream);
    k_deg<<<(NE + 255) / 256, 256, 0, stream>>>(dst, deg);
    k_dis<<<(NN + 255) / 256, 256, 0, stream>>>(deg, dis);
    k_norm<<<(NE + 255) / 256, 256, 0, stream>>>(src, dst, dis, nrm);
    // 4. GCN layers
    for (int l = 0; l < NL; l++) {
        k_rowmm<H><<<NN / 8, 128, 0, stream>>>(h, Wc + (size_t)l * H * H, nullptr, t, NN);
        hipMemsetAsync(agg, 0, (size_t)NN * H * 4, stream);
        if (e_f32)
            k_scatter<float><<<(NE * 32) / 256, 256, 0, stream>>>(t, (const float*)ebuf, nrm, src, dst, agg);
        else
            k_scatter<__hip_bfloat16><<<(NE * 32) / 256, 256, 0, stream>>>(t, (const __hip_bfloat16*)ebuf, nrm, src, dst, agg);
        k_finish<<<(NN * 32) / 256, 256, 0, stream>>>(agg, t, dis, bc + (size_t)l * H, h);
    }
    // 5. pooling + head
    hipMemsetAsync(g, 0, (size_t)NG * H * 4, stream);
    hipMemsetAsync(cnts, 0, (size_t)NG * 4, stream);
    k_count<<<(NN + 255) / 256, 256, 0, stream>>>(bat, cnts);
    k_pool<<<(NN * 32) / 256, 256, 0, stream>>>(h, bat, g);
    k_head<<<NG, 128, 0, stream>>>(g, cnts, Wl1, bl1, Wl2, bl2, out);
}

// Round 2
// 1211.214 us; speedup vs baseline: 3.3512x; 3.3512x over previous
//
#include <hip/hip_runtime.h>
#include <hip/hip_bf16.h>

#define DEVFN __device__ __forceinline__

constexpr int NN = 50000;   // nodes
constexpr int NE = 600000;  // edges
constexpr int NG = 256;     // graphs
constexpr int FN = 92;      // node feat
constexpr int FE = 50;      // edge feat
constexpr int H  = 128;     // hidden
constexpr int NL = 3;       // layers

static_assert(NE % 32 == 0, "edge tile");
static_assert(NN % 8 == 0, "node tile");

// ---------- dtype helpers (float or bf16 storage of e) ----------
DEVFN float4 load4e(const float* p) { return *reinterpret_cast<const float4*>(p); }
DEVFN float4 load4e(const __hip_bfloat16* p) {
    const ushort4 u = *reinterpret_cast<const ushort4*>(p);
    float4 r;
    r.x = __uint_as_float(((unsigned)u.x) << 16);
    r.y = __uint_as_float(((unsigned)u.y) << 16);
    r.z = __uint_as_float(((unsigned)u.z) << 16);
    r.w = __uint_as_float(((unsigned)u.w) << 16);
    return r;
}
DEVFN float2 load2e(const float* p) { return *reinterpret_cast<const float2*>(p); }
DEVFN float2 load2e(const __hip_bfloat16* p) {
    const ushort2 u = *reinterpret_cast<const ushort2*>(p);
    float2 r;
    r.x = __uint_as_float(((unsigned)u.x) << 16);
    r.y = __uint_as_float(((unsigned)u.y) << 16);
    return r;
}
DEVFN void store4e(float* p, float4 v) { *reinterpret_cast<float4*>(p) = v; }
DEVFN void store4e(__hip_bfloat16* p, float4 v) {
    p[0] = __float2bfloat16(v.x);
    p[1] = __float2bfloat16(v.y);
    p[2] = __float2bfloat16(v.z);
    p[3] = __float2bfloat16(v.w);
}

// ---------- out[r][f] = X[r,:K] @ W[:K,f] (+ bias) ----------
template<int K>
__global__ void k_rowmm(const float* __restrict__ X, const float* __restrict__ W,
                        const float* __restrict__ bias, float* __restrict__ out,
                        int nrows)
{
    __shared__ float xs[8][K];
    const int row0 = blockIdx.x * 8;
    const int f = threadIdx.x;
    for (int idx = threadIdx.x; idx < 8 * K; idx += 128) {
        const int r = idx / K, k = idx - r * K;
        const int gr = row0 + r;
        xs[r][k] = (gr < nrows) ? X[(size_t)gr * K + k] : 0.f;
    }
    __syncthreads();
    float acc[8];
#pragma unroll
    for (int r = 0; r < 8; r++) acc[r] = 0.f;
#pragma unroll 4
    for (int k = 0; k < K; k++) {
        const float w = W[k * H + f];
#pragma unroll
        for (int r = 0; r < 8; r++) acc[r] = fmaf(xs[r][k], w, acc[r]);
    }
    const float bb = bias ? bias[f] : 0.f;
#pragma unroll
    for (int r = 0; r < 8; r++) {
        const int gr = row0 + r;
        if (gr < nrows) out[(size_t)gr * H + f] = acc[r] + bb;
    }
}

// ---------- CSR build ----------
__global__ void k_deg(const int* __restrict__ dst, int* __restrict__ deg)
{
    const int e = blockIdx.x * 256 + threadIdx.x;
    if (e < NE) atomicAdd(&deg[dst[e]], 1);
}

// single-block exclusive scan over NN counts -> start[NN+1]
__global__ void k_scan(const int* __restrict__ deg, int* __restrict__ start)
{
    constexpr int T = 1024;
    __shared__ int partial[T];
    const int tid = threadIdx.x;
    const int chunk = (NN + T - 1) / T;
    const int base = tid * chunk;
    int sum = 0;
    for (int i = 0; i < chunk; i++) {
        const int idx = base + i;
        if (idx < NN) sum += deg[idx];
    }
    partial[tid] = sum;
    __syncthreads();
    for (int off = 1; off < T; off <<= 1) {
        const int v = (tid >= off) ? partial[tid - off] : 0;
        __syncthreads();
        partial[tid] += v;
        __syncthreads();
    }
    int run = (tid == 0) ? 0 : partial[tid - 1];
    for (int i = 0; i < chunk; i++) {
        const int idx = base + i;
        if (idx < NN) { start[idx] = run; run += deg[idx]; }
    }
    if (tid == T - 1) start[NN] = run;   // == NE
}

__global__ void k_place(const int* __restrict__ dst, const int* __restrict__ start,
                        int* __restrict__ cursor, int* __restrict__ perm)
{
    const int e = blockIdx.x * 256 + threadIdx.x;
    if (e < NE) {
        const int d = dst[e];
        const int r = atomicAdd(&cursor[d], 1);
        perm[start[d] + r] = e;
    }
}

// deterministic: sort each node's slice of perm by edge id (avg deg ~12)
__global__ void k_sortseg(const int* __restrict__ start, int* __restrict__ perm)
{
    const int n = blockIdx.x * 256 + threadIdx.x;
    if (n >= NN) return;
    const int s0 = start[n], s1 = start[n + 1];
    for (int i = s0 + 1; i < s1; i++) {
        const int v = perm[i];
        int j = i - 1;
        while (j >= s0 && perm[j] > v) { perm[j + 1] = perm[j]; j--; }
        perm[j + 1] = v;
    }
}

__global__ void k_dis(const int* __restrict__ deg, float* __restrict__ dis)
{
    const int n = blockIdx.x * 256 + threadIdx.x;
    if (n < NN) dis[n] = rsqrtf((float)deg[n] + 1.0f);
}

// ---------- edge MLP in dst-sorted order, norm folded in ----------
// writes eout[slot] = (relu(attr@W1+b1)@W2 + b2) * dis[src]*dis[dst]
template<typename ET>
__global__ void k_edge_mlp_perm(const float* __restrict__ attr,
                                const int* __restrict__ perm,
                                const int* __restrict__ src, const int* __restrict__ dst,
                                const float* __restrict__ dis,
                                const float* __restrict__ W1, const float* __restrict__ b1,
                                const float* __restrict__ W2, const float* __restrict__ b2,
                                ET* __restrict__ eout, int* __restrict__ srcperm)
{
    __shared__ float attr_s[32][FE + 2];
    __shared__ float tmp_s[32][H + 4];
    __shared__ int   eid_s[32];
    __shared__ float nrm_s[32];
    const int slot0 = blockIdx.x * 32;
    const int tg = threadIdx.x & 31;   // feature quad
    const int tr = threadIdx.x >> 5;   // edge quad group (0..7)
    const int f0 = tg * 4;

    if (threadIdx.x < 32) {
        const int eid = perm[slot0 + threadIdx.x];
        eid_s[threadIdx.x] = eid;
        const int s = src[eid], d = dst[eid];
        nrm_s[threadIdx.x] = dis[s] * dis[d];
        srcperm[slot0 + threadIdx.x] = s;
    }
    __syncthreads();
    for (int idx = threadIdx.x; idx < 32 * FE; idx += 256) {
        const int e = idx / FE, k = idx - e * FE;
        attr_s[e][k] = attr[(size_t)eid_s[e] * FE + k];
    }
    __syncthreads();

    float acc[4][4];
#pragma unroll
    for (int j = 0; j < 4; j++)
#pragma unroll
        for (int i = 0; i < 4; i++) acc[j][i] = 0.f;

#pragma unroll 2
    for (int k = 0; k < FE; k++) {
        const float4 w = *reinterpret_cast<const float4*>(&W1[k * H + f0]);
#pragma unroll
        for (int j = 0; j < 4; j++) {
            const float a = attr_s[tr * 4 + j][k];
            acc[j][0] = fmaf(a, w.x, acc[j][0]);
            acc[j][1] = fmaf(a, w.y, acc[j][1]);
            acc[j][2] = fmaf(a, w.z, acc[j][2]);
            acc[j][3] = fmaf(a, w.w, acc[j][3]);
        }
    }
    const float4 bb1 = *reinterpret_cast<const float4*>(&b1[f0]);
#pragma unroll
    for (int j = 0; j < 4; j++) {
        float4 v;
        v.x = fmaxf(acc[j][0] + bb1.x, 0.f);
        v.y = fmaxf(acc[j][1] + bb1.y, 0.f);
        v.z = fmaxf(acc[j][2] + bb1.z, 0.f);
        v.w = fmaxf(acc[j][3] + bb1.w, 0.f);
        *reinterpret_cast<float4*>(&tmp_s[tr * 4 + j][f0]) = v;
    }
    __syncthreads();

#pragma unroll
    for (int j = 0; j < 4; j++)
#pragma unroll
        for (int i = 0; i < 4; i++) acc[j][i] = 0.f;

#pragma unroll 2
    for (int k = 0; k < H; k++) {
        const float4 w = *reinterpret_cast<const float4*>(&W2[k * H + f0]);
#pragma unroll
        for (int j = 0; j < 4; j++) {
            const float a = tmp_s[tr * 4 + j][k];
            acc[j][0] = fmaf(a, w.x, acc[j][0]);
            acc[j][1] = fmaf(a, w.y, acc[j][1]);
            acc[j][2] = fmaf(a, w.z, acc[j][2]);
            acc[j][3] = fmaf(a, w.w, acc[j][3]);
        }
    }
    const float4 bb2 = *reinterpret_cast<const float4*>(&b2[f0]);
#pragma unroll
    for (int j = 0; j < 4; j++) {
        const float nm = nrm_s[tr * 4 + j];
        float4 v;
        v.x = (acc[j][0] + bb2.x) * nm;
        v.y = (acc[j][1] + bb2.y) * nm;
        v.z = (acc[j][2] + bb2.z) * nm;
        v.w = (acc[j][3] + bb2.w) * nm;
        store4e(&eout[(size_t)(slot0 + tr * 4 + j) * H + f0], v);
    }
}

// ---------- CSR aggregate + self-loop + bias + relu, fused ----------
// one wave per node; lane owns float2 of H
template<typename ET>
__global__ void k_agg(const float* __restrict__ t, const ET* __restrict__ eperm,
                      const int* __restrict__ srcperm, const int* __restrict__ start,
                      const float* __restrict__ dis, const float* __restrict__ bias,
                      float* __restrict__ h)
{
    const int node = (blockIdx.x * blockDim.x + threadIdx.x) >> 6;
    if (node >= NN) return;
    const int lane = threadIdx.x & 63;
    const int f0 = lane * 2;
    const int s0 = start[node], s1 = start[node + 1];

    float2 a0 = {0.f, 0.f}, a1 = {0.f, 0.f};
    int slot = s0;
    for (; slot + 2 <= s1; slot += 2) {
        const int sA = srcperm[slot];
        const int sB = srcperm[slot + 1];
        const float2 eA = load2e(&eperm[(size_t)slot * H + f0]);
        const float2 eB = load2e(&eperm[(size_t)(slot + 1) * H + f0]);
        const float2 tA = *reinterpret_cast<const float2*>(&t[(size_t)sA * H + f0]);
        const float2 tB = *reinterpret_cast<const float2*>(&t[(size_t)sB * H + f0]);
        a0.x = fmaf(tA.x, eA.x, a0.x);
        a0.y = fmaf(tA.y, eA.y, a0.y);
        a1.x = fmaf(tB.x, eB.x, a1.x);
        a1.y = fmaf(tB.y, eB.y, a1.y);
    }
    if (slot < s1) {
        const int sA = srcperm[slot];
        const float2 eA = load2e(&eperm[(size_t)slot * H + f0]);
        const float2 tA = *reinterpret_cast<const float2*>(&t[(size_t)sA * H + f0]);
        a0.x = fmaf(tA.x, eA.x, a0.x);
        a0.y = fmaf(tA.y, eA.y, a0.y);
    }
    const float ds = dis[node];
    const float d2 = ds * ds;
    const float2 tv = *reinterpret_cast<const float2*>(&t[(size_t)node * H + f0]);
    const float2 bb = *reinterpret_cast<const float2*>(&bias[f0]);
    float2 r;
    r.x = fmaxf(a0.x + a1.x + tv.x * d2 + bb.x, 0.f);
    r.y = fmaxf(a0.y + a1.y + tv.y * d2 + bb.y, 0.f);
    *reinterpret_cast<float2*>(&h[(size_t)node * H + f0]) = r;
}

// ---------- graph boundaries (batch is sorted) ----------
__global__ void k_bounds(const int* __restrict__ batch, int* __restrict__ gstart)
{
    const int g = blockIdx.x * blockDim.x + threadIdx.x;
    if (g > NG) return;
    int lo = 0, hi = NN;
    while (lo < hi) {
        const int mid = (lo + hi) >> 1;
        if (batch[mid] < g) lo = mid + 1; else hi = mid;
    }
    gstart[g] = lo;
}

// ---------- fused mean-pool + head ----------
__global__ void k_pool_head(const float* __restrict__ h, const int* __restrict__ gstart,
                            const float* __restrict__ W1, const float* __restrict__ b1,
                            const float* __restrict__ W2, const float* __restrict__ b2,
                            float* __restrict__ out)
{
    __shared__ float gs[H];
    __shared__ float red[2];
    const int gi = blockIdx.x;
    const int f = threadIdx.x;
    const int n0 = gstart[gi], n1 = gstart[gi + 1];
    float sum = 0.f;
    for (int n = n0; n < n1; n++) sum += h[(size_t)n * H + f];
    const float cnt = fmaxf((float)(n1 - n0), 1.0f);
    gs[f] = sum / cnt;
    __syncthreads();
    float acc = b1[f];
#pragma unroll 4
    for (int k = 0; k < H; k++) acc = fmaf(gs[k], W1[k * H + f], acc);
    float v = fmaxf(acc, 0.f) * W2[f];
#pragma unroll
    for (int off = 32; off > 0; off >>= 1) v += __shfl_down(v, off, 64);
    if ((f & 63) == 0) red[f >> 6] = v;
    __syncthreads();
    if (f == 0) out[gi] = red[0] + red[1] + b2[0];
}

extern "C" void kernel_launch(void* const* d_in, const int* in_sizes, int n_in,
                              void* d_out, int out_size, void* d_ws, size_t ws_size,
                              hipStream_t stream)
{
    const float* x    = (const float*)d_in[0];
    const float* attr = (const float*)d_in[1];
    const int*   ei   = (const int*)d_in[2];
    const int*   bat  = (const int*)d_in[3];
    const float* Wn   = (const float*)d_in[4];
    const float* bn   = (const float*)d_in[5];
    const float* We1  = (const float*)d_in[6];
    const float* be1  = (const float*)d_in[7];
    const float* We2  = (const float*)d_in[8];
    const float* be2  = (const float*)d_in[9];
    const float* Wc   = (const float*)d_in[10];
    const float* bc   = (const float*)d_in[11];
    const float* Wl1  = (const float*)d_in[12];
    const float* bl1  = (const float*)d_in[13];
    const float* Wl2  = (const float*)d_in[14];
    const float* bl2  = (const float*)d_in[15];
    float* out = (float*)d_out;
    const int* src = ei;
    const int* dst = ei + NE;

    auto aln = [](size_t v) { return (v + 255) & ~(size_t)255; };
    char* p = (char*)d_ws;
    auto carve = [&](size_t bytes) { char* r = p; p += aln(bytes); return r; };
    float* h       = (float*)carve((size_t)NN * H * 4);
    float* t       = (float*)carve((size_t)NN * H * 4);
    int*   deg     = (int*)  carve((size_t)NN * 4);
    int*   startC  = (int*)  carve((size_t)(NN + 1) * 4);
    int*   cursor  = (int*)  carve((size_t)NN * 4);
    float* dis     = (float*)carve((size_t)NN * 4);
    int*   perm    = (int*)  carve((size_t)NE * 4);
    int*   srcperm = (int*)  carve((size_t)NE * 4);
    int*   gstart  = (int*)  carve((size_t)(NG + 1) * 4);
    const size_t used = (size_t)(p - (char*)d_ws);
    const bool e_f32 = (ws_size >= used + (size_t)NE * H * 4);
    void* eperm = (void*)p;

    // CSR build (deterministic)
    hipMemsetAsync(deg, 0, (size_t)NN * 4, stream);
    hipMemsetAsync(cursor, 0, (size_t)NN * 4, stream);
    k_deg<<<(NE + 255) / 256, 256, 0, stream>>>(dst, deg);
    k_scan<<<1, 1024, 0, stream>>>(deg, startC);
    k_place<<<(NE + 255) / 256, 256, 0, stream>>>(dst, startC, cursor, perm);
    k_sortseg<<<(NN + 255) / 256, 256, 0, stream>>>(startC, perm);
    k_dis<<<(NN + 255) / 256, 256, 0, stream>>>(deg, dis);

    // node embedding
    k_rowmm<FN><<<NN / 8, 128, 0, stream>>>(x, Wn, bn, h, NN);

    // edge MLP in permuted order (norm folded)
    if (e_f32)
        k_edge_mlp_perm<float><<<NE / 32, 256, 0, stream>>>(
            attr, perm, src, dst, dis, We1, be1, We2, be2, (float*)eperm, srcperm);
    else
        k_edge_mlp_perm<__hip_bfloat16><<<NE / 32, 256, 0, stream>>>(
            attr, perm, src, dst, dis, We1, be1, We2, be2, (__hip_bfloat16*)eperm, srcperm);

    // GCN layers
    for (int l = 0; l < NL; l++) {
        k_rowmm<H><<<NN / 8, 128, 0, stream>>>(h, Wc + (size_t)l * H * H, nullptr, t, NN);
        if (e_f32)
            k_agg<float><<<(NN * 64 + 255) / 256, 256, 0, stream>>>(
                t, (const float*)eperm, srcperm, startC, dis, bc + (size_t)l * H, h);
        else
            k_agg<__hip_bfloat16><<<(NN * 64 + 255) / 256, 256, 0, stream>>>(
                t, (const __hip_bfloat16*)eperm, srcperm, startC, dis, bc + (size_t)l * H, h);
    }

    // fused pool + head
    k_bounds<<<2, 256, 0, stream>>>(bat, gstart);
    k_pool_head<<<NG, H, 0, stream>>>(h, gstart, Wl1, bl1, Wl2, bl2, out);
}

// Round 3
// 1077.976 us; speedup vs baseline: 3.7654x; 1.1236x over previous
//
#include <hip/hip_runtime.h>
#include <hip/hip_bf16.h>

#define DEVFN __device__ __forceinline__

typedef __attribute__((ext_vector_type(8))) short short8v;
typedef __attribute__((ext_vector_type(4))) float f32x4;

constexpr int NN = 50000;   // nodes
constexpr int NE = 600000;  // edges
constexpr int NG = 256;     // graphs
constexpr int FN = 92;      // node feat
constexpr int FE = 50;      // edge feat
constexpr int H  = 128;     // hidden
constexpr int NL = 3;       // layers
constexpr int TE = 256;     // edges per block in MFMA edge kernel
constexpr int NBLK_E = (NE + TE - 1) / TE;

// ---------- bf16 split helpers ----------
DEVFN ushort f2bf(float x) {
    unsigned u = __float_as_uint(x);
    unsigned r = (u + 0x7fffu + ((u >> 16) & 1u)) >> 16;   // RNE
    return (ushort)r;
}
DEVFN float bftof(ushort u) { return __uint_as_float(((unsigned)u) << 16); }

// ---------- out[r][f] = X[r,:K] @ W[:K,f] (+ bias) ----------
template<int K>
__global__ void k_rowmm(const float* __restrict__ X, const float* __restrict__ W,
                        const float* __restrict__ bias, float* __restrict__ out,
                        int nrows)
{
    __shared__ float xs[8][K];
    const int row0 = blockIdx.x * 8;
    const int f = threadIdx.x;
    for (int idx = threadIdx.x; idx < 8 * K; idx += 128) {
        const int r = idx / K, k = idx - r * K;
        const int gr = row0 + r;
        xs[r][k] = (gr < nrows) ? X[(size_t)gr * K + k] : 0.f;
    }
    __syncthreads();
    float acc[8];
#pragma unroll
    for (int r = 0; r < 8; r++) acc[r] = 0.f;
#pragma unroll 4
    for (int k = 0; k < K; k++) {
        const float w = W[k * H + f];
#pragma unroll
        for (int r = 0; r < 8; r++) acc[r] = fmaf(xs[r][k], w, acc[r]);
    }
    const float bb = bias ? bias[f] : 0.f;
#pragma unroll
    for (int r = 0; r < 8; r++) {
        const int gr = row0 + r;
        if (gr < nrows) out[(size_t)gr * H + f] = acc[r] + bb;
    }
}

// ---------- CSR build ----------
__global__ void k_deg(const int* __restrict__ dst, int* __restrict__ deg)
{
    const int e = blockIdx.x * 256 + threadIdx.x;
    if (e < NE) atomicAdd(&deg[dst[e]], 1);
}

__global__ void k_scan(const int* __restrict__ deg, int* __restrict__ start)
{
    constexpr int T = 1024;
    __shared__ int partial[T];
    const int tid = threadIdx.x;
    const int chunk = (NN + T - 1) / T;
    const int base = tid * chunk;
    int sum = 0;
    for (int i = 0; i < chunk; i++) {
        const int idx = base + i;
        if (idx < NN) sum += deg[idx];
    }
    partial[tid] = sum;
    __syncthreads();
    for (int off = 1; off < T; off <<= 1) {
        const int v = (tid >= off) ? partial[tid - off] : 0;
        __syncthreads();
        partial[tid] += v;
        __syncthreads();
    }
    int run = (tid == 0) ? 0 : partial[tid - 1];
    for (int i = 0; i < chunk; i++) {
        const int idx = base + i;
        if (idx < NN) { start[idx] = run; run += deg[idx]; }
    }
    if (tid == T - 1) start[NN] = run;
}

__global__ void k_place(const int* __restrict__ dst, const int* __restrict__ start,
                        int* __restrict__ cursor, int* __restrict__ perm)
{
    const int e = blockIdx.x * 256 + threadIdx.x;
    if (e < NE) {
        const int d = dst[e];
        const int r = atomicAdd(&cursor[d], 1);
        perm[start[d] + r] = e;
    }
}

__global__ void k_sortseg(const int* __restrict__ start, int* __restrict__ perm)
{
    const int n = blockIdx.x * 256 + threadIdx.x;
    if (n >= NN) return;
    const int s0 = start[n], s1 = start[n + 1];
    for (int i = s0 + 1; i < s1; i++) {
        const int v = perm[i];
        int j = i - 1;
        while (j >= s0 && perm[j] > v) { perm[j + 1] = perm[j]; j--; }
        perm[j + 1] = v;
    }
}

__global__ void k_dis(const int* __restrict__ deg, float* __restrict__ dis)
{
    const int n = blockIdx.x * 256 + threadIdx.x;
    if (n < NN) dis[n] = rsqrtf((float)deg[n] + 1.0f);
}

// ---------- prelude: pack W1/W2 into split-bf16 MFMA fragment layout ----------
// W1P: frag f1 = (ct*2+kc)*2+sp  (ct<8, kc<2, sp<2): entry [f1*512 + lane*8 + j]
//      = split_sp( W1[k][m] ), k = kc*32+(lane>>4)*8+j (0 if k>=FE), m = ct*16+(lane&15)
// W2P: frag f2 = (ct*4+kc)*2+sp  (ct<8, kc<4): same with W2, K=128.
__global__ void k_pack(const float* __restrict__ W1, const float* __restrict__ W2,
                       ushort* __restrict__ w1p, ushort* __restrict__ w2p)
{
    const int idx = blockIdx.x * 256 + threadIdx.x;
    if (idx < 32 * 512) {
        const int j = idx & 7, lane = (idx >> 3) & 63, sp = (idx >> 9) & 1;
        const int kc = (idx >> 10) & 1, ct = idx >> 11;
        const int k = kc * 32 + (lane >> 4) * 8 + j;
        const int m = ct * 16 + (lane & 15);
        const float w = (k < FE) ? W1[k * H + m] : 0.f;
        const ushort h = f2bf(w);
        w1p[idx] = (sp == 0) ? h : f2bf(w - bftof(h));
    }
    const int idx2 = idx - 32 * 512;
    if (idx2 >= 0 && idx2 < 64 * 512) {
        const int j = idx2 & 7, lane = (idx2 >> 3) & 63, sp = (idx2 >> 9) & 1;
        const int kc = (idx2 >> 10) & 3, ct = idx2 >> 12;
        const int k = kc * 32 + (lane >> 4) * 8 + j;
        const int m = ct * 16 + (lane & 15);
        const float w = W2[k * H + m];
        const ushort h = f2bf(w);
        w2p[idx2] = (sp == 0) ? h : f2bf(w - bftof(h));
    }
}

// ---------- MFMA edge MLP, dst-sorted order, norm folded ----------
// GEMM1 (transposed): D1[m=tmpcol][n=edge] = sum_k W1[k][m] * attr[edge][k]
//   a-frag = W1P (m = lane&15, k = kc*32+(lane>>4)*8+j)
//   b-frag = attr LDS (n = lane&15, same k)
//   D1: lane holds tmpcol = ct*16 + q*4 + reg, edge = et*16 + e  (q=lane>>4, e=lane&15)
// Bridge: shuffle 4-col quads into 8-col k-frags for GEMM2's B operand.
// GEMM2 (transposed): D2[m=outcol][n=edge], a-frag = W2P.
__global__ __launch_bounds__(512) void k_edge_mfma(
    const float* __restrict__ attr, const int* __restrict__ perm,
    const int* __restrict__ src, const int* __restrict__ dst,
    const float* __restrict__ dis,
    const ushort* __restrict__ w1p, const ushort* __restrict__ w2p,
    const float* __restrict__ b1, const float* __restrict__ b2,
    float* __restrict__ eout, int* __restrict__ srcperm)
{
    __shared__ unsigned ah_s[TE * 32];   // attr hi bf16 pairs, swizzled, 32KB
    __shared__ unsigned al_s[TE * 32];   // attr lo
    __shared__ float nrm_s[TE];
    __shared__ int   eid_s[TE];
    const int tid = threadIdx.x;
    const int slot0 = blockIdx.x * TE;

    if (tid < TE) {
        const int slot = slot0 + tid;
        const int eid = perm[min(slot, NE - 1)];
        eid_s[tid] = eid;
        const int s = src[eid], d = dst[eid];
        nrm_s[tid] = dis[s] * dis[d];
        if (slot < NE) srcperm[slot] = s;
    }
    __syncthreads();

    // gather + split attr rows -> swizzled LDS ([row][64k] bf16, byte ^= (row&7)<<4)
    for (int i = tid; i < TE * 25; i += 512) {
        const int row = i / 25, kp = i - row * 25;
        const float2 v = *(const float2*)&attr[(size_t)eid_s[row] * FE + kp * 2];
        const ushort hx = f2bf(v.x), hy = f2bf(v.y);
        const unsigned hw = (unsigned)hx | ((unsigned)hy << 16);
        const unsigned lw = (unsigned)f2bf(v.x - bftof(hx)) |
                            ((unsigned)f2bf(v.y - bftof(hy)) << 16);
        const int w = (row * 128 + ((kp * 4) ^ ((row & 7) << 4))) >> 2;
        ah_s[w] = hw; al_s[w] = lw;
    }
    for (int i = tid; i < TE * 7; i += 512) {   // zero-pad k = 50..63
        const int row = i / 7, wi = i - row * 7;
        const int w = (row * 128 + (((25 + wi) * 4) ^ ((row & 7) << 4))) >> 2;
        ah_s[w] = 0; al_s[w] = 0;
    }
    __syncthreads();

    const int wid = tid >> 6, lane = tid & 63;
    const int q = lane >> 4, e = lane & 15;
    const short8v* w1f = (const short8v*)w1p;
    const short8v* w2f = (const short8v*)w2p;

    f32x4 acc1[8][2];
#pragma unroll
    for (int ct = 0; ct < 8; ct++)
#pragma unroll
        for (int et = 0; et < 2; et++) acc1[ct][et] = (f32x4)0.f;

#pragma unroll
    for (int kc = 0; kc < 2; kc++) {
        short8v bh[2], bl[2];
#pragma unroll
        for (int et = 0; et < 2; et++) {
            const int row = (wid * 2 + et) * 16 + e;
            const int off = row * 128 + ((kc * 64 + q * 16) ^ ((row & 7) << 4));
            bh[et] = *(const short8v*)((const char*)ah_s + off);
            bl[et] = *(const short8v*)((const char*)al_s + off);
        }
#pragma unroll
        for (int ct = 0; ct < 8; ct++) {
            const short8v a_h = w1f[((ct * 2 + kc) * 2 + 0) * 64 + lane];
            const short8v a_l = w1f[((ct * 2 + kc) * 2 + 1) * 64 + lane];
#pragma unroll
            for (int et = 0; et < 2; et++) {
                acc1[ct][et] = __builtin_amdgcn_mfma_f32_16x16x32_bf16(a_h, bh[et], acc1[ct][et], 0, 0, 0);
                acc1[ct][et] = __builtin_amdgcn_mfma_f32_16x16x32_bf16(a_h, bl[et], acc1[ct][et], 0, 0, 0);
                acc1[ct][et] = __builtin_amdgcn_mfma_f32_16x16x32_bf16(a_l, bh[et], acc1[ct][et], 0, 0, 0);
            }
        }
    }

    f32x4 acc2[8][2];
#pragma unroll
    for (int ct = 0; ct < 8; ct++)
#pragma unroll
        for (int et = 0; et < 2; et++) acc2[ct][et] = (f32x4)0.f;

#pragma unroll
    for (int kc2 = 0; kc2 < 4; kc2++) {
        // lazy bridge: bias+relu+split+pack the two tmp-col tiles feeding this kc2
        unsigned Ph[2][2][2], Pl[2][2][2];   // [o][et][w2]
#pragma unroll
        for (int o = 0; o < 2; o++) {
            const int ct = kc2 * 2 + o;
            const float4 b1v = *(const float4*)&b1[ct * 16 + q * 4];
#pragma unroll
            for (int et = 0; et < 2; et++) {
                const float v0 = fmaxf(acc1[ct][et][0] + b1v.x, 0.f);
                const float v1 = fmaxf(acc1[ct][et][1] + b1v.y, 0.f);
                const float v2 = fmaxf(acc1[ct][et][2] + b1v.z, 0.f);
                const float v3 = fmaxf(acc1[ct][et][3] + b1v.w, 0.f);
                const ushort h0 = f2bf(v0), h1 = f2bf(v1), h2 = f2bf(v2), h3 = f2bf(v3);
                Ph[o][et][0] = (unsigned)h0 | ((unsigned)h1 << 16);
                Ph[o][et][1] = (unsigned)h2 | ((unsigned)h3 << 16);
                Pl[o][et][0] = (unsigned)f2bf(v0 - bftof(h0)) | ((unsigned)f2bf(v1 - bftof(h1)) << 16);
                Pl[o][et][1] = (unsigned)f2bf(v2 - bftof(h2)) | ((unsigned)f2bf(v3 - bftof(h3)) << 16);
            }
        }
        short8v tbh[2], tbl[2];
#pragma unroll
        for (int et = 0; et < 2; et++) {
            unsigned fh[4], fl[4];
#pragma unroll
            for (int b = 0; b < 2; b++) {
                const int srcL = e + 16 * (2 * (q & 1) + b);
#pragma unroll
                for (int w2 = 0; w2 < 2; w2++) {
#pragma unroll
                    for (int o = 0; o < 2; o++) {
                        const unsigned th = (unsigned)__shfl((int)Ph[o][et][w2], srcL, 64);
                        const unsigned tl = (unsigned)__shfl((int)Pl[o][et][w2], srcL, 64);
                        if ((q >> 1) == o) { fh[b * 2 + w2] = th; fl[b * 2 + w2] = tl; }
                    }
                }
            }
            union { unsigned u[4]; short8v s; } cvh, cvl;
            cvh.u[0] = fh[0]; cvh.u[1] = fh[1]; cvh.u[2] = fh[2]; cvh.u[3] = fh[3];
            cvl.u[0] = fl[0]; cvl.u[1] = fl[1]; cvl.u[2] = fl[2]; cvl.u[3] = fl[3];
            tbh[et] = cvh.s; tbl[et] = cvl.s;
        }
#pragma unroll
        for (int ct2 = 0; ct2 < 8; ct2++) {
            const short8v a_h = w2f[((ct2 * 4 + kc2) * 2 + 0) * 64 + lane];
            const short8v a_l = w2f[((ct2 * 4 + kc2) * 2 + 1) * 64 + lane];
#pragma unroll
            for (int et = 0; et < 2; et++) {
                acc2[ct2][et] = __builtin_amdgcn_mfma_f32_16x16x32_bf16(a_h, tbh[et], acc2[ct2][et], 0, 0, 0);
                acc2[ct2][et] = __builtin_amdgcn_mfma_f32_16x16x32_bf16(a_h, tbl[et], acc2[ct2][et], 0, 0, 0);
                acc2[ct2][et] = __builtin_amdgcn_mfma_f32_16x16x32_bf16(a_l, tbh[et], acc2[ct2][et], 0, 0, 0);
            }
        }
    }

    // epilogue: (acc2 + b2) * nrm -> eout[slot][col], float4 stores
#pragma unroll
    for (int ct2 = 0; ct2 < 8; ct2++) {
        const float4 b2v = *(const float4*)&b2[ct2 * 16 + q * 4];
#pragma unroll
        for (int et = 0; et < 2; et++) {
            const int erow = (wid * 2 + et) * 16 + e;
            const int slot = slot0 + erow;
            const float nm = nrm_s[erow];
            float4 ov;
            ov.x = (acc2[ct2][et][0] + b2v.x) * nm;
            ov.y = (acc2[ct2][et][1] + b2v.y) * nm;
            ov.z = (acc2[ct2][et][2] + b2v.z) * nm;
            ov.w = (acc2[ct2][et][3] + b2v.w) * nm;
            if (slot < NE)
                *(float4*)&eout[(size_t)slot * H + ct2 * 16 + q * 4] = ov;
        }
    }
}

// ---------- CSR aggregate + self-loop + bias + relu, fused ----------
__global__ void k_agg(const float* __restrict__ t, const float* __restrict__ eperm,
                      const int* __restrict__ srcperm, const int* __restrict__ start,
                      const float* __restrict__ dis, const float* __restrict__ bias,
                      float* __restrict__ h)
{
    const int node = (blockIdx.x * blockDim.x + threadIdx.x) >> 6;
    if (node >= NN) return;
    const int lane = threadIdx.x & 63;
    const int f0 = lane * 2;
    const int s0 = start[node], s1 = start[node + 1];

    float2 a0 = {0.f, 0.f}, a1 = {0.f, 0.f};
    int slot = s0;
    for (; slot + 2 <= s1; slot += 2) {
        const int sA = srcperm[slot];
        const int sB = srcperm[slot + 1];
        const float2 eA = *(const float2*)&eperm[(size_t)slot * H + f0];
        const float2 eB = *(const float2*)&eperm[(size_t)(slot + 1) * H + f0];
        const float2 tA = *(const float2*)&t[(size_t)sA * H + f0];
        const float2 tB = *(const float2*)&t[(size_t)sB * H + f0];
        a0.x = fmaf(tA.x, eA.x, a0.x);
        a0.y = fmaf(tA.y, eA.y, a0.y);
        a1.x = fmaf(tB.x, eB.x, a1.x);
        a1.y = fmaf(tB.y, eB.y, a1.y);
    }
    if (slot < s1) {
        const int sA = srcperm[slot];
        const float2 eA = *(const float2*)&eperm[(size_t)slot * H + f0];
        const float2 tA = *(const float2*)&t[(size_t)sA * H + f0];
        a0.x = fmaf(tA.x, eA.x, a0.x);
        a0.y = fmaf(tA.y, eA.y, a0.y);
    }
    const float ds = dis[node];
    const float d2 = ds * ds;
    const float2 tv = *(const float2*)&t[(size_t)node * H + f0];
    const float2 bb = *(const float2*)&bias[f0];
    float2 r;
    r.x = fmaxf(a0.x + a1.x + tv.x * d2 + bb.x, 0.f);
    r.y = fmaxf(a0.y + a1.y + tv.y * d2 + bb.y, 0.f);
    *(float2*)&h[(size_t)node * H + f0] = r;
}

// ---------- graph boundaries ----------
__global__ void k_bounds(const int* __restrict__ batch, int* __restrict__ gstart)
{
    const int g = blockIdx.x * blockDim.x + threadIdx.x;
    if (g > NG) return;
    int lo = 0, hi = NN;
    while (lo < hi) {
        const int mid = (lo + hi) >> 1;
        if (batch[mid] < g) lo = mid + 1; else hi = mid;
    }
    gstart[g] = lo;
}

// ---------- fused mean-pool + head ----------
__global__ void k_pool_head(const float* __restrict__ h, const int* __restrict__ gstart,
                            const float* __restrict__ W1, const float* __restrict__ b1,
                            const float* __restrict__ W2, const float* __restrict__ b2,
                            float* __restrict__ out)
{
    __shared__ float gs[H];
    __shared__ float red[2];
    const int gi = blockIdx.x;
    const int f = threadIdx.x;
    const int n0 = gstart[gi], n1 = gstart[gi + 1];
    float sum = 0.f;
    for (int n = n0; n < n1; n++) sum += h[(size_t)n * H + f];
    const float cnt = fmaxf((float)(n1 - n0), 1.0f);
    gs[f] = sum / cnt;
    __syncthreads();
    float acc = b1[f];
#pragma unroll 4
    for (int k = 0; k < H; k++) acc = fmaf(gs[k], W1[k * H + f], acc);
    float v = fmaxf(acc, 0.f) * W2[f];
#pragma unroll
    for (int off = 32; off > 0; off >>= 1) v += __shfl_down(v, off, 64);
    if ((f & 63) == 0) red[f >> 6] = v;
    __syncthreads();
    if (f == 0) out[gi] = red[0] + red[1] + b2[0];
}

extern "C" void kernel_launch(void* const* d_in, const int* in_sizes, int n_in,
                              void* d_out, int out_size, void* d_ws, size_t ws_size,
                              hipStream_t stream)
{
    const float* x    = (const float*)d_in[0];
    const float* attr = (const float*)d_in[1];
    const int*   ei   = (const int*)d_in[2];
    const int*   bat  = (const int*)d_in[3];
    const float* Wn   = (const float*)d_in[4];
    const float* bn   = (const float*)d_in[5];
    const float* We1  = (const float*)d_in[6];
    const float* be1  = (const float*)d_in[7];
    const float* We2  = (const float*)d_in[8];
    const float* be2  = (const float*)d_in[9];
    const float* Wc   = (const float*)d_in[10];
    const float* bc   = (const float*)d_in[11];
    const float* Wl1  = (const float*)d_in[12];
    const float* bl1  = (const float*)d_in[13];
    const float* Wl2  = (const float*)d_in[14];
    const float* bl2  = (const float*)d_in[15];
    float* out = (float*)d_out;
    const int* src = ei;
    const int* dst = ei + NE;

    auto aln = [](size_t v) { return (v + 255) & ~(size_t)255; };
    char* p = (char*)d_ws;
    auto carve = [&](size_t bytes) { char* r = p; p += aln(bytes); return r; };
    float*  h       = (float*)carve((size_t)NN * H * 4);
    float*  t       = (float*)carve((size_t)NN * H * 4);
    int*    deg     = (int*)  carve((size_t)NN * 4);
    int*    startC  = (int*)  carve((size_t)(NN + 1) * 4);
    int*    cursor  = (int*)  carve((size_t)NN * 4);
    float*  dis     = (float*)carve((size_t)NN * 4);
    int*    perm    = (int*)  carve((size_t)NE * 4);
    int*    srcperm = (int*)  carve((size_t)NE * 4);
    int*    gstart  = (int*)  carve((size_t)(NG + 1) * 4);
    ushort* w1p     = (ushort*)carve(32 * 512 * 2);
    ushort* w2p     = (ushort*)carve(64 * 512 * 2);
    float*  eperm   = (float*)carve((size_t)NE * H * 4);

    // CSR build (deterministic)
    hipMemsetAsync(deg, 0, (size_t)NN * 4, stream);
    hipMemsetAsync(cursor, 0, (size_t)NN * 4, stream);
    k_deg<<<(NE + 255) / 256, 256, 0, stream>>>(dst, deg);
    k_scan<<<1, 1024, 0, stream>>>(deg, startC);
    k_place<<<(NE + 255) / 256, 256, 0, stream>>>(dst, startC, cursor, perm);
    k_sortseg<<<(NN + 255) / 256, 256, 0, stream>>>(startC, perm);
    k_dis<<<(NN + 255) / 256, 256, 0, stream>>>(deg, dis);

    // weight packing for MFMA edge MLP
    k_pack<<<192, 256, 0, stream>>>(We1, We2, w1p, w2p);

    // node embedding
    k_rowmm<FN><<<NN / 8, 128, 0, stream>>>(x, Wn, bn, h, NN);

    // edge MLP (MFMA, split-bf16, permuted order, norm folded)
    k_edge_mfma<<<NBLK_E, 512, 0, stream>>>(attr, perm, src, dst, dis,
                                            w1p, w2p, be1, be2, eperm, srcperm);

    // GCN layers
    for (int l = 0; l < NL; l++) {
        k_rowmm<H><<<NN / 8, 128, 0, stream>>>(h, Wc + (size_t)l * H * H, nullptr, t, NN);
        k_agg<<<(NN * 64 + 255) / 256, 256, 0, stream>>>(
            t, eperm, srcperm, startC, dis, bc + (size_t)l * H, h);
    }

    // fused pool + head
    k_bounds<<<2, 256, 0, stream>>>(bat, gstart);
    k_pool_head<<<NG, H, 0, stream>>>(h, gstart, Wl1, bl1, Wl2, bl2, out);
}

// Round 4
// 851.327 us; speedup vs baseline: 4.7679x; 1.2662x over previous
//
#include <hip/hip_runtime.h>
#include <hip/hip_bf16.h>

#define DEVFN __device__ __forceinline__

typedef __attribute__((ext_vector_type(8))) short short8v;
typedef __attribute__((ext_vector_type(4))) float f32x4;

constexpr int NN = 50000;   // nodes
constexpr int NE = 600000;  // edges
constexpr int NG = 256;     // graphs
constexpr int FN = 92;      // node feat
constexpr int FE = 50;      // edge feat
constexpr int H  = 128;     // hidden
constexpr int NL = 3;       // layers
constexpr int TE = 128;     // edges per block in MFMA edge kernel
constexpr int NBLK_E = (NE + TE - 1) / TE;

// ---------- bf16 helpers ----------
DEVFN ushort f2bf(float x) {
    unsigned u = __float_as_uint(x);
    unsigned r = (u + 0x7fffu + ((u >> 16) & 1u)) >> 16;   // RNE
    return (ushort)r;
}
DEVFN float bftof(ushort u) { return __uint_as_float(((unsigned)u) << 16); }

DEVFN float2 load2e(const float* p) { return *reinterpret_cast<const float2*>(p); }
DEVFN float2 load2e(const __hip_bfloat16* p) {
    const ushort2 u = *reinterpret_cast<const ushort2*>(p);
    float2 r;
    r.x = __uint_as_float(((unsigned)u.x) << 16);
    r.y = __uint_as_float(((unsigned)u.y) << 16);
    return r;
}

// ---------- out[r][f] = X[r,:K] @ W[:K,f] (+ bias) ----------
template<int K>
__global__ void k_rowmm(const float* __restrict__ X, const float* __restrict__ W,
                        const float* __restrict__ bias, float* __restrict__ out,
                        int nrows)
{
    __shared__ float xs[8][K];
    const int row0 = blockIdx.x * 8;
    const int f = threadIdx.x;
    for (int idx = threadIdx.x; idx < 8 * K; idx += 128) {
        const int r = idx / K, k = idx - r * K;
        const int gr = row0 + r;
        xs[r][k] = (gr < nrows) ? X[(size_t)gr * K + k] : 0.f;
    }
    __syncthreads();
    float acc[8];
#pragma unroll
    for (int r = 0; r < 8; r++) acc[r] = 0.f;
#pragma unroll 4
    for (int k = 0; k < K; k++) {
        const float w = W[k * H + f];
#pragma unroll
        for (int r = 0; r < 8; r++) acc[r] = fmaf(xs[r][k], w, acc[r]);
    }
    const float bb = bias ? bias[f] : 0.f;
#pragma unroll
    for (int r = 0; r < 8; r++) {
        const int gr = row0 + r;
        if (gr < nrows) out[(size_t)gr * H + f] = acc[r] + bb;
    }
}

// ---------- CSR build ----------
__global__ void k_deg(const int* __restrict__ dst, int* __restrict__ deg)
{
    const int e = blockIdx.x * 256 + threadIdx.x;
    if (e < NE) atomicAdd(&deg[dst[e]], 1);
}

__global__ void k_scan(const int* __restrict__ deg, int* __restrict__ start)
{
    constexpr int T = 1024;
    __shared__ int partial[T];
    const int tid = threadIdx.x;
    const int chunk = (NN + T - 1) / T;
    const int base = tid * chunk;
    int sum = 0;
    for (int i = 0; i < chunk; i++) {
        const int idx = base + i;
        if (idx < NN) sum += deg[idx];
    }
    partial[tid] = sum;
    __syncthreads();
    for (int off = 1; off < T; off <<= 1) {
        const int v = (tid >= off) ? partial[tid - off] : 0;
        __syncthreads();
        partial[tid] += v;
        __syncthreads();
    }
    int run = (tid == 0) ? 0 : partial[tid - 1];
    for (int i = 0; i < chunk; i++) {
        const int idx = base + i;
        if (idx < NN) { start[idx] = run; run += deg[idx]; }
    }
    if (tid == T - 1) start[NN] = run;
}

__global__ void k_place(const int* __restrict__ dst, const int* __restrict__ start,
                        int* __restrict__ cursor, int* __restrict__ perm)
{
    const int e = blockIdx.x * 256 + threadIdx.x;
    if (e < NE) {
        const int d = dst[e];
        const int r = atomicAdd(&cursor[d], 1);
        perm[start[d] + r] = e;
    }
}

__global__ void k_sortseg(const int* __restrict__ start, int* __restrict__ perm)
{
    const int n = blockIdx.x * 256 + threadIdx.x;
    if (n >= NN) return;
    const int s0 = start[n], s1 = start[n + 1];
    for (int i = s0 + 1; i < s1; i++) {
        const int v = perm[i];
        int j = i - 1;
        while (j >= s0 && perm[j] > v) { perm[j + 1] = perm[j]; j--; }
        perm[j + 1] = v;
    }
}

__global__ void k_dis(const int* __restrict__ deg, float* __restrict__ dis)
{
    const int n = blockIdx.x * 256 + threadIdx.x;
    if (n < NN) dis[n] = rsqrtf((float)deg[n] + 1.0f);
}

// ---------- prelude: pack W1/W2 into split-bf16 MFMA fragment layout ----------
// W1P: frag f1 = (ct*2+kc)*2+sp  (ct<8, kc<2, sp<2): entry [f1*512 + lane*8 + j]
//      = split_sp( W1[k][m] ), k = kc*32+(lane>>4)*8+j (0 if k>=FE), m = ct*16+(lane&15)
// W2P: frag f2 = (ct*4+kc)*2+sp  (ct<8, kc<4): same with W2, K=128.
__global__ void k_pack(const float* __restrict__ W1, const float* __restrict__ W2,
                       ushort* __restrict__ w1p, ushort* __restrict__ w2p)
{
    const int idx = blockIdx.x * 256 + threadIdx.x;
    if (idx < 32 * 512) {
        const int j = idx & 7, lane = (idx >> 3) & 63, sp = (idx >> 9) & 1;
        const int kc = (idx >> 10) & 1, ct = idx >> 11;
        const int k = kc * 32 + (lane >> 4) * 8 + j;
        const int m = ct * 16 + (lane & 15);
        const float w = (k < FE) ? W1[k * H + m] : 0.f;
        const ushort h = f2bf(w);
        w1p[idx] = (sp == 0) ? h : f2bf(w - bftof(h));
    }
    const int idx2 = idx - 32 * 512;
    if (idx2 >= 0 && idx2 < 64 * 512) {
        const int j = idx2 & 7, lane = (idx2 >> 3) & 63, sp = (idx2 >> 9) & 1;
        const int kc = (idx2 >> 10) & 3, ct = idx2 >> 12;
        const int k = kc * 32 + (lane >> 4) * 8 + j;
        const int m = ct * 16 + (lane & 15);
        const float w = W2[k * H + m];
        const ushort h = f2bf(w);
        w2p[idx2] = (sp == 0) ? h : f2bf(w - bftof(h));
    }
}

// ---------- MFMA edge MLP, dst-sorted order, norm folded, bf16 out ----------
// GEMM1 (transposed): D1[m=tmpcol][n=edge], A = W1 split, B = attr bf16 (LDS).
// Bridge: D1 quads -> tmp LDS (swizzled bf16) -> B-frags for GEMM2.
// GEMM2 (transposed): D2[m=outcol][n=edge], A = W2 split, B = tmp bf16.
// Two column-half passes so tmp LDS is TE*64 bf16 (16 KB).
__global__ __launch_bounds__(256, 3) void k_edge_mfma(
    const float* __restrict__ attr, const int* __restrict__ perm,
    const int* __restrict__ src, const int* __restrict__ dst,
    const float* __restrict__ dis,
    const ushort* __restrict__ w1p, const ushort* __restrict__ w2p,
    const float* __restrict__ b1, const float* __restrict__ b2,
    ushort* __restrict__ eout, int* __restrict__ srcperm)
{
    __shared__ unsigned ah_s[TE * 32];    // attr bf16 [row][64k], swizzled, 16KB
    __shared__ unsigned tmp_s[TE * 32];   // tmp bf16 [row][64c], swizzled, 16KB
    __shared__ float nrm_s[TE];
    __shared__ int   eid_s[TE];
    const int tid = threadIdx.x;
    const int slot0 = blockIdx.x * TE;

    if (tid < TE) {
        const int slot = slot0 + tid;
        const int eid = perm[min(slot, NE - 1)];
        eid_s[tid] = eid;
        nrm_s[tid] = dis[src[eid]] * dis[dst[eid]];
        if (slot < NE) srcperm[slot] = src[eid];
    }
    __syncthreads();

    // stage attr (plain bf16) -> swizzled LDS; zero-pad k = 50..63
    for (int i = tid; i < TE * 32; i += 256) {
        const int row = i >> 5, w = i & 31;
        unsigned hw = 0;
        if (w < 25) {
            const float2 v = *(const float2*)&attr[(size_t)eid_s[row] * FE + w * 2];
            hw = (unsigned)f2bf(v.x) | ((unsigned)f2bf(v.y) << 16);
        }
        ah_s[(row * 128 + ((w * 4) ^ ((row & 7) << 4))) >> 2] = hw;
    }
    __syncthreads();

    const int wid = tid >> 6, lane = tid & 63;
    const int q = lane >> 4, e = lane & 15;
    const int rowA = (wid * 2 + 0) * 16 + e;
    const int rowB = (wid * 2 + 1) * 16 + e;
    const short8v* w1f = (const short8v*)w1p;
    const short8v* w2f = (const short8v*)w2p;

    f32x4 acc2[8][2];
#pragma unroll
    for (int ct = 0; ct < 8; ct++)
#pragma unroll
        for (int et = 0; et < 2; et++) acc2[ct][et] = (f32x4)0.f;

#pragma unroll
    for (int p = 0; p < 2; p++) {
        // ---- GEMM1: tmp cols [p*64, p*64+64) ----
        f32x4 acc1[4][2];
#pragma unroll
        for (int c = 0; c < 4; c++)
#pragma unroll
            for (int et = 0; et < 2; et++) acc1[c][et] = (f32x4)0.f;

#pragma unroll
        for (int kc = 0; kc < 2; kc++) {
            const short8v bA = *(const short8v*)((const char*)ah_s +
                rowA * 128 + ((kc * 64 + q * 16) ^ ((rowA & 7) << 4)));
            const short8v bB = *(const short8v*)((const char*)ah_s +
                rowB * 128 + ((kc * 64 + q * 16) ^ ((rowB & 7) << 4)));
#pragma unroll
            for (int c = 0; c < 4; c++) {
                const int ct = p * 4 + c;
                const short8v a_h = w1f[((ct * 2 + kc) * 2 + 0) * 64 + lane];
                const short8v a_l = w1f[((ct * 2 + kc) * 2 + 1) * 64 + lane];
                acc1[c][0] = __builtin_amdgcn_mfma_f32_16x16x32_bf16(a_h, bA, acc1[c][0], 0, 0, 0);
                acc1[c][0] = __builtin_amdgcn_mfma_f32_16x16x32_bf16(a_l, bA, acc1[c][0], 0, 0, 0);
                acc1[c][1] = __builtin_amdgcn_mfma_f32_16x16x32_bf16(a_h, bB, acc1[c][1], 0, 0, 0);
                acc1[c][1] = __builtin_amdgcn_mfma_f32_16x16x32_bf16(a_l, bB, acc1[c][1], 0, 0, 0);
            }
        }

        if (p == 1) __syncthreads();   // all GEMM2a tmp reads done before overwrite

        // ---- bias + relu + bf16 pack -> tmp LDS ----
#pragma unroll
        for (int c = 0; c < 4; c++) {
            const int ct = p * 4 + c;
            const float4 b1v = *(const float4*)&b1[ct * 16 + q * 4];
#pragma unroll
            for (int et = 0; et < 2; et++) {
                const int row = (wid * 2 + et) * 16 + e;
                const float v0 = fmaxf(acc1[c][et][0] + b1v.x, 0.f);
                const float v1 = fmaxf(acc1[c][et][1] + b1v.y, 0.f);
                const float v2 = fmaxf(acc1[c][et][2] + b1v.z, 0.f);
                const float v3 = fmaxf(acc1[c][et][3] + b1v.w, 0.f);
                unsigned* dptr = &tmp_s[(row * 128 + ((c * 32 + q * 8) ^ ((row & 7) << 4))) >> 2];
                dptr[0] = (unsigned)f2bf(v0) | ((unsigned)f2bf(v1) << 16);
                dptr[1] = (unsigned)f2bf(v2) | ((unsigned)f2bf(v3) << 16);
            }
        }
        __syncthreads();

        // ---- GEMM2: kc2 = 2p, 2p+1 ----
#pragma unroll
        for (int kk = 0; kk < 2; kk++) {
            const int kc2 = p * 2 + kk;
            const short8v tA = *(const short8v*)((const char*)tmp_s +
                rowA * 128 + ((kk * 64 + q * 16) ^ ((rowA & 7) << 4)));
            const short8v tB = *(const short8v*)((const char*)tmp_s +
                rowB * 128 + ((kk * 64 + q * 16) ^ ((rowB & 7) << 4)));
#pragma unroll
            for (int ct2 = 0; ct2 < 8; ct2++) {
                const short8v a_h = w2f[((ct2 * 4 + kc2) * 2 + 0) * 64 + lane];
                const short8v a_l = w2f[((ct2 * 4 + kc2) * 2 + 1) * 64 + lane];
                acc2[ct2][0] = __builtin_amdgcn_mfma_f32_16x16x32_bf16(a_h, tA, acc2[ct2][0], 0, 0, 0);
                acc2[ct2][0] = __builtin_amdgcn_mfma_f32_16x16x32_bf16(a_l, tA, acc2[ct2][0], 0, 0, 0);
                acc2[ct2][1] = __builtin_amdgcn_mfma_f32_16x16x32_bf16(a_h, tB, acc2[ct2][1], 0, 0, 0);
                acc2[ct2][1] = __builtin_amdgcn_mfma_f32_16x16x32_bf16(a_l, tB, acc2[ct2][1], 0, 0, 0);
            }
        }
    }

    // ---- epilogue: (acc2 + b2) * nrm -> bf16 eout ----
#pragma unroll
    for (int ct2 = 0; ct2 < 8; ct2++) {
        const float4 b2v = *(const float4*)&b2[ct2 * 16 + q * 4];
#pragma unroll
        for (int et = 0; et < 2; et++) {
            const int row = (wid * 2 + et) * 16 + e;
            const int slot = slot0 + row;
            const float nm = nrm_s[row];
            ushort4 ov;
            ov.x = f2bf((acc2[ct2][et][0] + b2v.x) * nm);
            ov.y = f2bf((acc2[ct2][et][1] + b2v.y) * nm);
            ov.z = f2bf((acc2[ct2][et][2] + b2v.z) * nm);
            ov.w = f2bf((acc2[ct2][et][3] + b2v.w) * nm);
            if (slot < NE)
                *(ushort4*)&eout[(size_t)slot * H + ct2 * 16 + q * 4] = ov;
        }
    }
}

// ---------- CSR aggregate + self-loop + bias + relu, fused ----------
template<typename ET>
__global__ void k_agg(const float* __restrict__ t, const ET* __restrict__ eperm,
                      const int* __restrict__ srcperm, const int* __restrict__ start,
                      const float* __restrict__ dis, const float* __restrict__ bias,
                      float* __restrict__ h)
{
    const int node = (blockIdx.x * blockDim.x + threadIdx.x) >> 6;
    if (node >= NN) return;
    const int lane = threadIdx.x & 63;
    const int f0 = lane * 2;
    const int s0 = start[node], s1 = start[node + 1];

    float2 a0 = {0.f, 0.f}, a1 = {0.f, 0.f};
    int slot = s0;
    for (; slot + 2 <= s1; slot += 2) {
        const int sA = srcperm[slot];
        const int sB = srcperm[slot + 1];
        const float2 eA = load2e(&eperm[(size_t)slot * H + f0]);
        const float2 eB = load2e(&eperm[(size_t)(slot + 1) * H + f0]);
        const float2 tA = *(const float2*)&t[(size_t)sA * H + f0];
        const float2 tB = *(const float2*)&t[(size_t)sB * H + f0];
        a0.x = fmaf(tA.x, eA.x, a0.x);
        a0.y = fmaf(tA.y, eA.y, a0.y);
        a1.x = fmaf(tB.x, eB.x, a1.x);
        a1.y = fmaf(tB.y, eB.y, a1.y);
    }
    if (slot < s1) {
        const int sA = srcperm[slot];
        const float2 eA = load2e(&eperm[(size_t)slot * H + f0]);
        const float2 tA = *(const float2*)&t[(size_t)sA * H + f0];
        a0.x = fmaf(tA.x, eA.x, a0.x);
        a0.y = fmaf(tA.y, eA.y, a0.y);
    }
    const float ds = dis[node];
    const float d2 = ds * ds;
    const float2 tv = *(const float2*)&t[(size_t)node * H + f0];
    const float2 bb = *(const float2*)&bias[f0];
    float2 r;
    r.x = fmaxf(a0.x + a1.x + tv.x * d2 + bb.x, 0.f);
    r.y = fmaxf(a0.y + a1.y + tv.y * d2 + bb.y, 0.f);
    *(float2*)&h[(size_t)node * H + f0] = r;
}

// ---------- graph boundaries ----------
__global__ void k_bounds(const int* __restrict__ batch, int* __restrict__ gstart)
{
    const int g = blockIdx.x * blockDim.x + threadIdx.x;
    if (g > NG) return;
    int lo = 0, hi = NN;
    while (lo < hi) {
        const int mid = (lo + hi) >> 1;
        if (batch[mid] < g) lo = mid + 1; else hi = mid;
    }
    gstart[g] = lo;
}

// ---------- fused mean-pool + head ----------
__global__ void k_pool_head(const float* __restrict__ h, const int* __restrict__ gstart,
                            const float* __restrict__ W1, const float* __restrict__ b1,
                            const float* __restrict__ W2, const float* __restrict__ b2,
                            float* __restrict__ out)
{
    __shared__ float gs[H];
    __shared__ float red[2];
    const int gi = blockIdx.x;
    const int f = threadIdx.x;
    const int n0 = gstart[gi], n1 = gstart[gi + 1];
    float sum = 0.f;
    for (int n = n0; n < n1; n++) sum += h[(size_t)n * H + f];
    const float cnt = fmaxf((float)(n1 - n0), 1.0f);
    gs[f] = sum / cnt;
    __syncthreads();
    float acc = b1[f];
#pragma unroll 4
    for (int k = 0; k < H; k++) acc = fmaf(gs[k], W1[k * H + f], acc);
    float v = fmaxf(acc, 0.f) * W2[f];
#pragma unroll
    for (int off = 32; off > 0; off >>= 1) v += __shfl_down(v, off, 64);
    if ((f & 63) == 0) red[f >> 6] = v;
    __syncthreads();
    if (f == 0) out[gi] = red[0] + red[1] + b2[0];
}

extern "C" void kernel_launch(void* const* d_in, const int* in_sizes, int n_in,
                              void* d_out, int out_size, void* d_ws, size_t ws_size,
                              hipStream_t stream)
{
    const float* x    = (const float*)d_in[0];
    const float* attr = (const float*)d_in[1];
    const int*   ei   = (const int*)d_in[2];
    const int*   bat  = (const int*)d_in[3];
    const float* Wn   = (const float*)d_in[4];
    const float* bn   = (const float*)d_in[5];
    const float* We1  = (const float*)d_in[6];
    const float* be1  = (const float*)d_in[7];
    const float* We2  = (const float*)d_in[8];
    const float* be2  = (const float*)d_in[9];
    const float* Wc   = (const float*)d_in[10];
    const float* bc   = (const float*)d_in[11];
    const float* Wl1  = (const float*)d_in[12];
    const float* bl1  = (const float*)d_in[13];
    const float* Wl2  = (const float*)d_in[14];
    const float* bl2  = (const float*)d_in[15];
    float* out = (float*)d_out;
    const int* src = ei;
    const int* dst = ei + NE;

    auto aln = [](size_t v) { return (v + 255) & ~(size_t)255; };
    char* p = (char*)d_ws;
    auto carve = [&](size_t bytes) { char* r = p; p += aln(bytes); return r; };
    float*  h       = (float*)carve((size_t)NN * H * 4);
    float*  t       = (float*)carve((size_t)NN * H * 4);
    int*    deg     = (int*)  carve((size_t)NN * 4);
    int*    startC  = (int*)  carve((size_t)(NN + 1) * 4);
    int*    cursor  = (int*)  carve((size_t)NN * 4);
    float*  dis     = (float*)carve((size_t)NN * 4);
    int*    perm    = (int*)  carve((size_t)NE * 4);
    int*    srcperm = (int*)  carve((size_t)NE * 4);
    int*    gstart  = (int*)  carve((size_t)(NG + 1) * 4);
    ushort* w1p     = (ushort*)carve(32 * 512 * 2);
    ushort* w2p     = (ushort*)carve(64 * 512 * 2);
    ushort* eperm   = (ushort*)carve((size_t)NE * H * 2);

    // CSR build (deterministic)
    hipMemsetAsync(deg, 0, (size_t)NN * 4, stream);
    hipMemsetAsync(cursor, 0, (size_t)NN * 4, stream);
    k_deg<<<(NE + 255) / 256, 256, 0, stream>>>(dst, deg);
    k_scan<<<1, 1024, 0, stream>>>(deg, startC);
    k_place<<<(NE + 255) / 256, 256, 0, stream>>>(dst, startC, cursor, perm);
    k_sortseg<<<(NN + 255) / 256, 256, 0, stream>>>(startC, perm);
    k_dis<<<(NN + 255) / 256, 256, 0, stream>>>(deg, dis);

    // weight packing for MFMA edge MLP
    k_pack<<<192, 256, 0, stream>>>(We1, We2, w1p, w2p);

    // node embedding
    k_rowmm<FN><<<NN / 8, 128, 0, stream>>>(x, Wn, bn, h, NN);

    // edge MLP (MFMA, split weights, bf16 activations, norm folded, bf16 out)
    k_edge_mfma<<<NBLK_E, 256, 0, stream>>>(attr, perm, src, dst, dis,
                                            w1p, w2p, be1, be2, eperm, srcperm);

    // GCN layers
    for (int l = 0; l < NL; l++) {
        k_rowmm<H><<<NN / 8, 128, 0, stream>>>(h, Wc + (size_t)l * H * H, nullptr, t, NN);
        k_agg<__hip_bfloat16><<<(NN * 64 + 255) / 256, 256, 0, stream>>>(
            t, (const __hip_bfloat16*)eperm, srcperm, startC, dis, bc + (size_t)l * H, h);
    }

    // fused pool + head
    k_bounds<<<2, 256, 0, stream>>>(bat, gstart);
    k_pool_head<<<NG, H, 0, stream>>>(h, gstart, Wl1, bl1, Wl2, bl2, out);
}